// Round 1
// baseline (7540.435 us; speedup 1.0000x reference)
//
#include <hip/hip_runtime.h>
#include <hip/hip_bf16.h>

#define T_TOK 2048
#define H_DIM 1024
#define E_NUM 32
#define I_DIM 768
#define TOPK  4
#define TM    32
#define TI    64
#define KC    64
#define MAXTILE (T_TOK / TM)   // 64

// ---- workspace layout (bytes) ----
#define OFF_IDX     0                   // int   [T*K]
#define OFF_TKW     (32*1024)           // float [T*K]
#define OFF_COUNTS  (64*1024)           // int   [E]
#define OFF_OFFSETS (65*1024)           // int   [E+1]
#define OFF_CURSORS (66*1024)           // int   [E]
#define OFF_PERM    (68*1024)           // int   [T*K]
#define OFF_PAIRW   (100*1024)          // float [T*K]
#define OFF_POS     (132*1024)          // int   [T*K]
#define OFF_H       (1024*1024)         // float [T*K][I]  25.2 MB
#define OFF_Y       (27*1024*1024)      // float [T*K][H]  33.6 MB
// total ~61 MB

// ---------------- router: logits -> softmax -> top4 -> renorm ----------------
__global__ __launch_bounds__(64)
void k_router(const float* __restrict__ x, const float* __restrict__ rw,
              int* __restrict__ idx, float* __restrict__ tkw, int* __restrict__ counts)
{
    int t = blockIdx.x;
    int lane = threadIdx.x;
    const float4* xr = (const float4*)(x + (size_t)t * H_DIM);
    float4 xv[4];
#pragma unroll
    for (int m = 0; m < 4; ++m) xv[m] = xr[m * 64 + lane];

    __shared__ float logits[E_NUM];
    for (int e = 0; e < E_NUM; ++e) {
        const float4* wr = (const float4*)(rw + (size_t)e * H_DIM);
        float acc = 0.f;
#pragma unroll
        for (int m = 0; m < 4; ++m) {
            float4 wv = wr[m * 64 + lane];
            acc += xv[m].x * wv.x + xv[m].y * wv.y + xv[m].z * wv.z + xv[m].w * wv.w;
        }
#pragma unroll
        for (int s = 32; s > 0; s >>= 1) acc += __shfl_xor(acc, s);
        if (lane == 0) logits[e] = acc;
    }
    __syncthreads();
    if (lane == 0) {
        float m = -1e30f;
        for (int e = 0; e < E_NUM; ++e) m = fmaxf(m, logits[e]);
        // exp(l - m); the softmax Z cancels in the top-k renormalization
        for (int e = 0; e < E_NUM; ++e) logits[e] = expf(logits[e] - m);
        float vals[TOPK]; int ids[TOPK]; float s = 0.f;
        for (int k = 0; k < TOPK; ++k) {
            float bv = -1.f; int be = 0;
            for (int e = 0; e < E_NUM; ++e)
                if (logits[e] > bv) { bv = logits[e]; be = e; }  // strict > : ties -> lowest index (jax)
            vals[k] = bv; ids[k] = be; logits[be] = -2.f; s += bv;
        }
        float invs = 1.f / s;
        for (int k = 0; k < TOPK; ++k) {
            idx[t * TOPK + k] = ids[k];
            tkw[t * TOPK + k] = vals[k] * invs;
            atomicAdd(&counts[ids[k]], 1);
        }
    }
}

// ---------------- scan (tiny) ----------------
__global__ void k_scan(const int* __restrict__ counts, int* __restrict__ offsets,
                       int* __restrict__ cursors)
{
    if (threadIdx.x == 0) {
        int acc = 0;
        for (int e = 0; e < E_NUM; ++e) { offsets[e] = acc; cursors[e] = acc; acc += counts[e]; }
        offsets[E_NUM] = acc;
    }
}

// ---------------- scatter pairs into per-expert groups ----------------
__global__ __launch_bounds__(256)
void k_scatter(const int* __restrict__ idx, const float* __restrict__ tkw,
               int* __restrict__ cursors, int* __restrict__ perm,
               float* __restrict__ pairw, int* __restrict__ pos)
{
    int g = blockIdx.x * 256 + threadIdx.x;
    if (g >= T_TOK * TOPK) return;
    int e = idx[g];
    int p = atomicAdd(&cursors[e], 1);
    perm[p] = g >> 2;        // token id
    pairw[p] = tkw[g];
    pos[g] = p;
}

// ---------------- gate/up GEMM + SiLU ----------------
// block: 256 thr; wave w owns rows 8w..8w+7, lane c owns intermediate col (ib+c)
__global__ __launch_bounds__(256)
void k_gateup(const float* __restrict__ x, const float* __restrict__ gw,
              const float* __restrict__ uw, const int* __restrict__ offsets,
              const int* __restrict__ perm, float* __restrict__ h)
{
    int e = blockIdx.z;
    int r0 = offsets[e], r1 = offsets[e + 1];
    int row0 = r0 + blockIdx.x * TM;
    if (row0 >= r1) return;
    int nrows = min(TM, r1 - row0);
    int ib = blockIdx.y * TI;

    __shared__ float xs[TM][KC + 4];
    __shared__ float gs[TI][KC + 4];
    __shared__ float us[TI][KC + 4];
    __shared__ int rtok[TM];

    int tid = threadIdx.x;
    if (tid < TM) rtok[tid] = perm[row0 + min(tid, nrows - 1)];

    const float* wgb = gw + ((size_t)e * I_DIM + ib) * H_DIM;
    const float* wub = uw + ((size_t)e * I_DIM + ib) * H_DIM;

    int wv = tid >> 6;
    int c  = tid & 63;
    float accg[8] = {0,0,0,0,0,0,0,0};
    float accu[8] = {0,0,0,0,0,0,0,0};

    for (int kb = 0; kb < H_DIM; kb += KC) {
        __syncthreads();
#pragma unroll
        for (int it = 0; it < 2; ++it) {               // 512 float4 of x tile
            int q = tid + it * 256;
            int r = q >> 4, k4 = (q & 15) << 2;
            *(float4*)&xs[r][k4] = *(const float4*)(x + (size_t)rtok[r] * H_DIM + kb + k4);
        }
#pragma unroll
        for (int it = 0; it < 4; ++it) {               // 1024 float4 each of wg, wu
            int q = tid + it * 256;
            int i = q >> 4, k4 = (q & 15) << 2;
            *(float4*)&gs[i][k4] = *(const float4*)(wgb + (size_t)i * H_DIM + kb + k4);
            *(float4*)&us[i][k4] = *(const float4*)(wub + (size_t)i * H_DIM + kb + k4);
        }
        __syncthreads();
#pragma unroll
        for (int kk = 0; kk < KC; kk += 4) {
            float4 g = *(const float4*)&gs[c][kk];
            float4 u = *(const float4*)&us[c][kk];
#pragma unroll
            for (int j = 0; j < 8; ++j) {
                float4 a = *(const float4*)&xs[8 * wv + j][kk];
                accg[j] += a.x * g.x + a.y * g.y + a.z * g.z + a.w * g.w;
                accu[j] += a.x * u.x + a.y * u.y + a.z * u.z + a.w * u.w;
            }
        }
    }
#pragma unroll
    for (int j = 0; j < 8; ++j) {
        int r = 8 * wv + j;
        if (r < nrows) {
            float gv = accg[j];
            float hv = (gv / (1.f + expf(-gv))) * accu[j];   // silu(g) * u
            h[(size_t)(row0 + r) * I_DIM + ib + c] = hv;
        }
    }
}

// ---------------- down GEMM, scaled by combine weight ----------------
__global__ __launch_bounds__(256)
void k_down(const float* __restrict__ dw, const int* __restrict__ offsets,
            const float* __restrict__ pairw, const float* __restrict__ h,
            float* __restrict__ y)
{
    int e = blockIdx.z;
    int r0 = offsets[e], r1 = offsets[e + 1];
    int row0 = r0 + blockIdx.x * TM;
    if (row0 >= r1) return;
    int nrows = min(TM, r1 - row0);
    int cb = blockIdx.y * TI;

    __shared__ float hs[TM][KC + 4];
    __shared__ float ds[TI][KC + 4];
    __shared__ float pw[TM];

    int tid = threadIdx.x;
    if (tid < TM) pw[tid] = pairw[row0 + min(tid, nrows - 1)];

    const float* wdb = dw + ((size_t)e * H_DIM + cb) * I_DIM;
    int wv = tid >> 6;
    int c  = tid & 63;
    float acc[8] = {0,0,0,0,0,0,0,0};

    for (int kb = 0; kb < I_DIM; kb += KC) {
        __syncthreads();
#pragma unroll
        for (int it = 0; it < 2; ++it) {
            int q = tid + it * 256;
            int r = q >> 4, k4 = (q & 15) << 2;
            int rr = min(row0 + r, r1 - 1);
            *(float4*)&hs[r][k4] = *(const float4*)(h + (size_t)rr * I_DIM + kb + k4);
        }
#pragma unroll
        for (int it = 0; it < 4; ++it) {
            int q = tid + it * 256;
            int i = q >> 4, k4 = (q & 15) << 2;
            *(float4*)&ds[i][k4] = *(const float4*)(wdb + (size_t)i * I_DIM + kb + k4);
        }
        __syncthreads();
#pragma unroll
        for (int kk = 0; kk < KC; kk += 4) {
            float4 d = *(const float4*)&ds[c][kk];
#pragma unroll
            for (int j = 0; j < 8; ++j) {
                float4 a = *(const float4*)&hs[8 * wv + j][kk];
                acc[j] += a.x * d.x + a.y * d.y + a.z * d.z + a.w * d.w;
            }
        }
    }
#pragma unroll
    for (int j = 0; j < 8; ++j) {
        int r = 8 * wv + j;
        if (r < nrows)
            y[(size_t)(row0 + r) * H_DIM + cb + c] = pw[r] * acc[j];
    }
}

// ---------------- deterministic 4-way combine ----------------
__global__ __launch_bounds__(256)
void k_combine(const float* __restrict__ y, const int* __restrict__ pos,
               float* __restrict__ out)
{
    int g = blockIdx.x * 256 + threadIdx.x;
    int t = g >> 10;          // H_DIM = 1024
    int hc = g & 1023;
    const int* pp = pos + t * TOPK;
    float s = y[(size_t)pp[0] * H_DIM + hc] + y[(size_t)pp[1] * H_DIM + hc]
            + y[(size_t)pp[2] * H_DIM + hc] + y[(size_t)pp[3] * H_DIM + hc];
    out[g] = s;
}

extern "C" void kernel_launch(void* const* d_in, const int* in_sizes, int n_in,
                              void* d_out, int out_size, void* d_ws, size_t ws_size,
                              hipStream_t stream)
{
    const float* x  = (const float*)d_in[0];   // [1,2048,1024]
    const float* rw = (const float*)d_in[1];   // [32,1024]
    const float* gw = (const float*)d_in[2];   // [32,768,1024]
    const float* uw = (const float*)d_in[3];   // [32,768,1024]
    const float* dw = (const float*)d_in[4];   // [32,1024,768]
    float* out = (float*)d_out;

    char* ws = (char*)d_ws;
    int*   idx     = (int*)  (ws + OFF_IDX);
    float* tkw     = (float*)(ws + OFF_TKW);
    int*   counts  = (int*)  (ws + OFF_COUNTS);
    int*   offsets = (int*)  (ws + OFF_OFFSETS);
    int*   cursors = (int*)  (ws + OFF_CURSORS);
    int*   perm    = (int*)  (ws + OFF_PERM);
    float* pairw   = (float*)(ws + OFF_PAIRW);
    int*   pos     = (int*)  (ws + OFF_POS);
    float* hbuf    = (float*)(ws + OFF_H);
    float* ybuf    = (float*)(ws + OFF_Y);

    hipMemsetAsync(ws + OFF_COUNTS, 0, 128, stream);

    k_router<<<T_TOK, 64, 0, stream>>>(x, rw, idx, tkw, counts);
    k_scan<<<1, 64, 0, stream>>>(counts, offsets, cursors);
    k_scatter<<<(T_TOK * TOPK + 255) / 256, 256, 0, stream>>>(idx, tkw, cursors, perm, pairw, pos);

    dim3 g3(MAXTILE, I_DIM / TI, E_NUM);   // (64, 12, 32)
    k_gateup<<<g3, 256, 0, stream>>>(x, gw, uw, offsets, perm, hbuf);

    dim3 g4(MAXTILE, H_DIM / TI, E_NUM);   // (64, 16, 32)
    k_down<<<g4, 256, 0, stream>>>(dw, offsets, pairw, hbuf, ybuf);

    k_combine<<<T_TOK * H_DIM / 256, 256, 0, stream>>>(ybuf, pos, out);
}

// Round 6
// 479.161 us; speedup vs baseline: 15.7368x; 15.7368x over previous
//
#include <hip/hip_runtime.h>
#include <hip/hip_bf16.h>

typedef __attribute__((ext_vector_type(8))) short short8;
typedef __attribute__((ext_vector_type(4))) float f32x4;

#define T_TOK 2048
#define H_DIM 1024
#define E_NUM 32
#define I_DIM 768
#define TOPK  4
#define NPAIR (T_TOK*TOPK)

// ---- workspace layout (bytes) ----
#define OFF_IDX     0                   // int   [NPAIR]
#define OFF_TKW     (32*1024)           // float [NPAIR]
#define OFF_COUNTS  (64*1024)           // int   [E]
#define OFF_OFFSETS (65*1024)           // int   [E+1]
#define OFF_CURSORS (66*1024)           // int   [E]
#define OFF_PERM    (68*1024)           // int   [NPAIR]
#define OFF_PAIRW   (100*1024)          // float [NPAIR]
#define OFF_POS     (132*1024)          // int   [NPAIR]
#define OFF_XBF     (1024*1024)         // bf16  [T][H]      4 MB
#define OFF_H       (6*1024*1024)       // bf16  [NPAIR][I]  12.6 MB
#define OFF_Y       (20*1024*1024)      // float [NPAIR][H]  33.6 MB
// total ~54 MB

__device__ __forceinline__ unsigned short f2bf(float f) {
    __hip_bfloat16 b = __float2bfloat16(f);
    unsigned short u;
    __builtin_memcpy(&u, &b, 2);
    return u;
}
__device__ __forceinline__ unsigned int pk2(float lo, float hi) {
    return (unsigned int)f2bf(lo) | ((unsigned int)f2bf(hi) << 16);
}

// ---------------- x fp32 -> bf16 ----------------
__global__ __launch_bounds__(256)
void k_xcvt(const float* __restrict__ x, unsigned short* __restrict__ xbf)
{
    int g = blockIdx.x * 256 + threadIdx.x;   // 8 elems per thread
    const float4* p = (const float4*)(x + (size_t)g * 8);
    float4 a = p[0], b = p[1];
    uint4 o = { pk2(a.x,a.y), pk2(a.z,a.w), pk2(b.x,b.y), pk2(b.z,b.w) };
    *(uint4*)(xbf + (size_t)g * 8) = o;
}

// ---------------- router: logits -> softmax -> top4 -> renorm ----------------
__global__ __launch_bounds__(64)
void k_router(const float* __restrict__ x, const float* __restrict__ rw,
              int* __restrict__ idx, float* __restrict__ tkw, int* __restrict__ counts)
{
    int t = blockIdx.x;
    int lane = threadIdx.x;
    const float4* xr = (const float4*)(x + (size_t)t * H_DIM);
    float4 xv[4];
#pragma unroll
    for (int m = 0; m < 4; ++m) xv[m] = xr[m * 64 + lane];

    __shared__ float logits[E_NUM];
    for (int e = 0; e < E_NUM; ++e) {
        const float4* wr = (const float4*)(rw + (size_t)e * H_DIM);
        float acc = 0.f;
#pragma unroll
        for (int m = 0; m < 4; ++m) {
            float4 wv = wr[m * 64 + lane];
            acc += xv[m].x * wv.x + xv[m].y * wv.y + xv[m].z * wv.z + xv[m].w * wv.w;
        }
#pragma unroll
        for (int s = 32; s > 0; s >>= 1) acc += __shfl_xor(acc, s);
        if (lane == 0) logits[e] = acc;
    }
    __syncthreads();
    if (lane == 0) {
        float m = -1e30f;
        for (int e = 0; e < E_NUM; ++e) m = fmaxf(m, logits[e]);
        for (int e = 0; e < E_NUM; ++e) logits[e] = expf(logits[e] - m);
        float vals[TOPK]; int ids[TOPK]; float s = 0.f;
        for (int k = 0; k < TOPK; ++k) {
            float bv = -1.f; int be = 0;
            for (int e = 0; e < E_NUM; ++e)
                if (logits[e] > bv) { bv = logits[e]; be = e; }
            vals[k] = bv; ids[k] = be; logits[be] = -2.f; s += bv;
        }
        float invs = 1.f / s;
        for (int k = 0; k < TOPK; ++k) {
            idx[t * TOPK + k] = ids[k];
            tkw[t * TOPK + k] = vals[k] * invs;
            atomicAdd(&counts[ids[k]], 1);
        }
    }
}

__global__ void k_scan(const int* __restrict__ counts, int* __restrict__ offsets,
                       int* __restrict__ cursors)
{
    if (threadIdx.x == 0) {
        int acc = 0;
        for (int e = 0; e < E_NUM; ++e) { offsets[e] = acc; cursors[e] = acc; acc += counts[e]; }
        offsets[E_NUM] = acc;
    }
}

__global__ __launch_bounds__(256)
void k_scatter(const int* __restrict__ idx, const float* __restrict__ tkw,
               int* __restrict__ cursors, int* __restrict__ perm,
               float* __restrict__ pairw, int* __restrict__ pos)
{
    int g = blockIdx.x * 256 + threadIdx.x;
    if (g >= NPAIR) return;
    int e = idx[g];
    int p = atomicAdd(&cursors[e], 1);
    perm[p] = g >> 2;
    pairw[p] = tkw[g];
    pos[g] = p;
}

// ---------------- gate/up MFMA GEMM + SiLU  (C[pair][i], A=x_bf, B=W^T rows) ----
#define GU_BN 64
#define GU_BM 256
#define GU_BK 64
#define PAD   72      // 64 + 8 bf16 elems; 144 B row stride -> ~2-way bank aliasing

__global__ __launch_bounds__(256, 2)
void k_gateup(const unsigned short* __restrict__ xbf, const float* __restrict__ gw,
              const float* __restrict__ uw, const int* __restrict__ offsets,
              const int* __restrict__ perm, unsigned short* __restrict__ h)
{
    int e  = blockIdx.z;
    int r0 = offsets[e], r1 = offsets[e + 1];
    int row0 = r0 + blockIdx.y * GU_BM;        // blockIdx.x = N-tile (XCD spread)
    if (row0 >= r1) return;
    int nrows = min(GU_BM, r1 - row0);
    int ib = blockIdx.x * GU_BN;

    __shared__ __align__(16) unsigned short As[GU_BM * PAD];   // 36864 B
    __shared__ __align__(16) unsigned short Bgs[GU_BN * PAD];  //  9216 B
    __shared__ __align__(16) unsigned short Bus[GU_BN * PAD];  //  9216 B
    __shared__ int rtok[GU_BM];

    int tid = threadIdx.x;
    rtok[tid] = perm[min(row0 + tid, r1 - 1)];

    const float* wgb = gw + ((size_t)e * I_DIM + ib) * H_DIM;
    const float* wub = uw + ((size_t)e * I_DIM + ib) * H_DIM;

    int w = tid >> 6;
    int lane = tid & 63;
    int l15 = lane & 15, lhi = lane >> 4;

    f32x4 accg[4][4], accu[4][4];
#pragma unroll
    for (int a = 0; a < 4; ++a)
#pragma unroll
        for (int b = 0; b < 4; ++b) { accg[a][b] = 0.f; accu[a][b] = 0.f; }

    for (int kb = 0; kb < H_DIM; kb += GU_BK) {
        __syncthreads();
        // A: 256 rows x 64 k bf16 (gathered), 2048 x 16B chunks
#pragma unroll
        for (int p = 0; p < 8; ++p) {
            int q = tid + p * 256;
            int row = q >> 3, kg = q & 7;
            uint4 v = *(const uint4*)(xbf + (size_t)rtok[row] * H_DIM + kb + kg * 8);
            *(uint4*)&As[row * PAD + kg * 8] = v;
        }
        // B gate/up: 64 rows x 64 k fp32 -> bf16 in staging
#pragma unroll
        for (int p = 0; p < 2; ++p) {
            int q = tid + p * 256;
            int row = q >> 3, kg = q & 7;
            const float* sg = wgb + (size_t)row * H_DIM + kb + kg * 8;
            float4 a0 = *(const float4*)sg, a1 = *(const float4*)(sg + 4);
            uint4 vg = { pk2(a0.x,a0.y), pk2(a0.z,a0.w), pk2(a1.x,a1.y), pk2(a1.z,a1.w) };
            *(uint4*)&Bgs[row * PAD + kg * 8] = vg;
            const float* su = wub + (size_t)row * H_DIM + kb + kg * 8;
            float4 b0 = *(const float4*)su, b1 = *(const float4*)(su + 4);
            uint4 vu = { pk2(b0.x,b0.y), pk2(b0.z,b0.w), pk2(b1.x,b1.y), pk2(b1.z,b1.w) };
            *(uint4*)&Bus[row * PAD + kg * 8] = vu;
        }
        __syncthreads();
#pragma unroll
        for (int kk = 0; kk < 2; ++kk) {
            short8 av[4], bgv[4], buv[4];
            int ko = kk * 32 + lhi * 8;
#pragma unroll
            for (int f = 0; f < 4; ++f) {
                av[f]  = *(const short8*)&As[(w * 64 + f * 16 + l15) * PAD + ko];
                bgv[f] = *(const short8*)&Bgs[(f * 16 + l15) * PAD + ko];
                buv[f] = *(const short8*)&Bus[(f * 16 + l15) * PAD + ko];
            }
#pragma unroll
            for (int fm = 0; fm < 4; ++fm)
#pragma unroll
                for (int fn = 0; fn < 4; ++fn) {
                    accg[fm][fn] = __builtin_amdgcn_mfma_f32_16x16x32_bf16(av[fm], bgv[fn], accg[fm][fn], 0, 0, 0);
                    accu[fm][fn] = __builtin_amdgcn_mfma_f32_16x16x32_bf16(av[fm], buv[fn], accu[fm][fn], 0, 0, 0);
                }
        }
    }
    // epilogue: h = silu(g) * u   (C frag: col = lane&15, row = (lane>>4)*4 + j)
#pragma unroll
    for (int fm = 0; fm < 4; ++fm) {
#pragma unroll
        for (int j = 0; j < 4; ++j) {
            int r = w * 64 + fm * 16 + lhi * 4 + j;
            if (r < nrows) {
                size_t orow = (size_t)(row0 + r) * I_DIM + ib + l15;
#pragma unroll
                for (int fn = 0; fn < 4; ++fn) {
                    float g = accg[fm][fn][j];
                    float u = accu[fm][fn][j];
                    float hv = (g / (1.f + __expf(-g))) * u;
                    h[orow + fn * 16] = f2bf(hv);
                }
            }
        }
    }
}

// ---------------- down MFMA GEMM, scaled by combine weight ----------------
#define DN_BN 64
#define DN_BM 256
#define DN_BK 64

__global__ __launch_bounds__(256, 2)
void k_down(const float* __restrict__ dw, const int* __restrict__ offsets,
            const float* __restrict__ pairw, const unsigned short* __restrict__ h,
            float* __restrict__ y)
{
    int e  = blockIdx.z;
    int r0 = offsets[e], r1 = offsets[e + 1];
    int row0 = r0 + blockIdx.y * DN_BM;
    if (row0 >= r1) return;
    int nrows = min(DN_BM, r1 - row0);
    int cb = blockIdx.x * DN_BN;

    __shared__ __align__(16) unsigned short As[DN_BM * PAD];
    __shared__ __align__(16) unsigned short Bs[DN_BN * PAD];
    __shared__ float pw[DN_BM];

    int tid = threadIdx.x;
    pw[tid] = pairw[min(row0 + tid, r1 - 1)];

    const float* wdb = dw + ((size_t)e * H_DIM + cb) * I_DIM;
    int w = tid >> 6, lane = tid & 63;
    int l15 = lane & 15, lhi = lane >> 4;

    f32x4 acc[4][4];
#pragma unroll
    for (int a = 0; a < 4; ++a)
#pragma unroll
        for (int b = 0; b < 4; ++b) acc[a][b] = 0.f;

    for (int kb = 0; kb < I_DIM; kb += DN_BK) {
        __syncthreads();
#pragma unroll
        for (int p = 0; p < 8; ++p) {
            int q = tid + p * 256;
            int row = q >> 3, kg = q & 7;
            int rr = min(row0 + row, r1 - 1);
            uint4 v = *(const uint4*)(h + (size_t)rr * I_DIM + kb + kg * 8);
            *(uint4*)&As[row * PAD + kg * 8] = v;
        }
#pragma unroll
        for (int p = 0; p < 2; ++p) {
            int q = tid + p * 256;
            int row = q >> 3, kg = q & 7;
            const float* sd = wdb + (size_t)row * I_DIM + kb + kg * 8;
            float4 a0 = *(const float4*)sd, a1 = *(const float4*)(sd + 4);
            uint4 vd = { pk2(a0.x,a0.y), pk2(a0.z,a0.w), pk2(a1.x,a1.y), pk2(a1.z,a1.w) };
            *(uint4*)&Bs[row * PAD + kg * 8] = vd;
        }
        __syncthreads();
#pragma unroll
        for (int kk = 0; kk < 2; ++kk) {
            short8 av[4], bv[4];
            int ko = kk * 32 + lhi * 8;
#pragma unroll
            for (int f = 0; f < 4; ++f) {
                av[f] = *(const short8*)&As[(w * 64 + f * 16 + l15) * PAD + ko];
                bv[f] = *(const short8*)&Bs[(f * 16 + l15) * PAD + ko];
            }
#pragma unroll
            for (int fm = 0; fm < 4; ++fm)
#pragma unroll
                for (int fn = 0; fn < 4; ++fn)
                    acc[fm][fn] = __builtin_amdgcn_mfma_f32_16x16x32_bf16(av[fm], bv[fn], acc[fm][fn], 0, 0, 0);
        }
    }
#pragma unroll
    for (int fm = 0; fm < 4; ++fm) {
#pragma unroll
        for (int j = 0; j < 4; ++j) {
            int r = w * 64 + fm * 16 + lhi * 4 + j;
            if (r < nrows) {
                float s = pw[r];
                size_t orow = (size_t)(row0 + r) * H_DIM + cb + l15;
#pragma unroll
                for (int fn = 0; fn < 4; ++fn)
                    y[orow + fn * 16] = s * acc[fm][fn][j];
            }
        }
    }
}

// ---------------- deterministic 4-way combine ----------------
__global__ __launch_bounds__(256)
void k_combine(const float* __restrict__ y, const int* __restrict__ pos,
               float* __restrict__ out)
{
    int g = blockIdx.x * 256 + threadIdx.x;
    int t = g >> 10;
    int hc = g & 1023;
    const int* pp = pos + t * TOPK;
    float s = y[(size_t)pp[0] * H_DIM + hc] + y[(size_t)pp[1] * H_DIM + hc]
            + y[(size_t)pp[2] * H_DIM + hc] + y[(size_t)pp[3] * H_DIM + hc];
    out[g] = s;
}

extern "C" void kernel_launch(void* const* d_in, const int* in_sizes, int n_in,
                              void* d_out, int out_size, void* d_ws, size_t ws_size,
                              hipStream_t stream)
{
    const float* x  = (const float*)d_in[0];   // [1,2048,1024]
    const float* rw = (const float*)d_in[1];   // [32,1024]
    const float* gw = (const float*)d_in[2];   // [32,768,1024]
    const float* uw = (const float*)d_in[3];   // [32,768,1024]
    const float* dw = (const float*)d_in[4];   // [32,1024,768]
    float* out = (float*)d_out;

    char* ws = (char*)d_ws;
    int*   idx     = (int*)  (ws + OFF_IDX);
    float* tkw     = (float*)(ws + OFF_TKW);
    int*   counts  = (int*)  (ws + OFF_COUNTS);
    int*   offsets = (int*)  (ws + OFF_OFFSETS);
    int*   cursors = (int*)  (ws + OFF_CURSORS);
    int*   perm    = (int*)  (ws + OFF_PERM);
    float* pairw   = (float*)(ws + OFF_PAIRW);
    int*   pos     = (int*)  (ws + OFF_POS);
    unsigned short* xbf = (unsigned short*)(ws + OFF_XBF);
    unsigned short* h   = (unsigned short*)(ws + OFF_H);
    float* y            = (float*)(ws + OFF_Y);

    hipMemsetAsync(counts, 0, E_NUM * sizeof(int), stream);

    k_xcvt<<<T_TOK * H_DIM / (256 * 8), 256, 0, stream>>>(x, xbf);
    k_router<<<T_TOK, 64, 0, stream>>>(x, rw, idx, tkw, counts);
    k_scan<<<1, 64, 0, stream>>>(counts, offsets, cursors);
    k_scatter<<<(NPAIR + 255) / 256, 256, 0, stream>>>(idx, tkw, cursors, perm, pairw, pos);

    dim3 g3(I_DIM / GU_BN, NPAIR / GU_BM, E_NUM);   // (12, 32, 32)
    k_gateup<<<g3, 256, 0, stream>>>(xbf, gw, uw, offsets, perm, h);

    dim3 g4(H_DIM / DN_BN, NPAIR / DN_BM, E_NUM);   // (16, 32, 32)
    k_down<<<g4, 256, 0, stream>>>(dw, offsets, pairw, h, y);

    k_combine<<<T_TOK * H_DIM / 256, 256, 0, stream>>>(y, pos, out);
}